// Round 6
// baseline (212.078 us; speedup 1.0000x reference)
//
#include <hip/hip_runtime.h>
#include <hip/hip_bf16.h>

// Sizes (fixed by the problem)
#define BB    8
#define DIMC  512
#define IMGS  32
#define NPIX  1024   // IMGS*IMGS
#define NHEAD 8
#define DHEAD 64

// Q pre-scale: DH^-0.5 * log2(e).  attn uses exp2 instead of exp, so the
// ln->log2 conversion is folded into the (already folded) 0.125 q scale.
#define QSC 0.18033688011112043f

typedef __attribute__((ext_vector_type(8))) short short8;
typedef __attribute__((ext_vector_type(4))) float float4v;

__device__ __forceinline__ float b2f(unsigned short u) {
  union { unsigned int i; float f; } c;
  c.i = ((unsigned int)u) << 16;
  return c.f;
}
// fp32 -> bf16 bits, round-to-nearest-even
__device__ __forceinline__ unsigned short f2b(float f) {
  union { float f; unsigned int u; } c;
  c.f = f;
  unsigned int r = c.u + 0x7fffu + ((c.u >> 16) & 1u);
  return (unsigned short)(r >> 16);
}
// fp32 -> bf16 bits, round-half-up (2 VALU ops; P is positive & finite,
// differs from RNE only on exact-halfway ULPs; softmax normalization
// cancels the tiny bias)
__device__ __forceinline__ unsigned short f2b_fast(float f) {
  union { float f; unsigned int u; } c;
  c.f = f;
  return (unsigned short)((c.u + 0x8000u) >> 16);
}

__device__ __forceinline__ void storeC(float* p, float v) { *p = v; }
__device__ __forceinline__ void storeC(unsigned short* p, float v) { *p = f2b(v); }

// async global -> LDS, 16 bytes per lane. LDS dest must be wave-uniform base
// + lane*16 (HW constraint) — all call sites below satisfy that.
__device__ __forceinline__ void async16(const void* g, void* l) {
  __builtin_amdgcn_global_load_lds(
      (const __attribute__((address_space(1))) void*)g,
      (__attribute__((address_space(3))) void*)l, 16, 0, 0);
}

// s_waitcnt immediates (gfx9 encoding: vmcnt[3:0]+[15:14], exp[6:4], lgkm[11:8])
#define WAITCNT_VM0   0x0F70   // vmcnt(0), others max
#define WAITCNT_VM4   0x0F74   // vmcnt(4), others max
#define WAITCNT_LGKM0 0xC07F   // lgkmcnt(0), others max

// ---------------------------------------------------------------------------
// Kernel 0: weight prep.
//  (a) pw_w (3*512*512) and out_w (512*512) fp32 -> bf16; q block (first
//      512*512) pre-scaled by QSC (=DH^-0.5 * log2e). Scaled bias bb[3*512].
//  (b) depthwise prep: wT[i][tap][512] = dw_w[i][c][tap] * bnscale[i][c],
//      shiftv[i][512] = (dw_b - bn_m)*bnscale + bn_b  (BN folded into conv).
// ---------------------------------------------------------------------------
__global__ __launch_bounds__(256) void wcvt_kernel(
    const float* __restrict__ pw_w, const float* __restrict__ out_w,
    const float* __restrict__ pw_b, const float* __restrict__ dw_w,
    const float* __restrict__ dw_b, const float* __restrict__ bn_g,
    const float* __restrict__ bn_b, const float* __restrict__ bn_m,
    const float* __restrict__ bn_v, unsigned short* __restrict__ wbf,
    float* __restrict__ bb, float* __restrict__ wT,
    float* __restrict__ shiftv) {
  const int i4 = (blockIdx.x * 256 + threadIdx.x) * 4;
  float4 v = (i4 < 3 * DIMC * DIMC)
                 ? *reinterpret_cast<const float4*>(pw_w + i4)
                 : *reinterpret_cast<const float4*>(out_w + (i4 - 3 * DIMC * DIMC));
  const float sc = (i4 < DIMC * DIMC) ? QSC : 1.0f;
  ushort4 o;
  o.x = f2b(v.x * sc); o.y = f2b(v.y * sc); o.z = f2b(v.z * sc); o.w = f2b(v.w * sc);
  *reinterpret_cast<ushort4*>(wbf + i4) = o;
  const int idx = blockIdx.x * 256 + threadIdx.x;
  if (idx < 6 * 256) {
    if (idx < 3 * DIMC / 2) {
      #pragma unroll
      for (int hh = 0; hh < 2; ++hh) {
        const int id2 = idx * 2 + hh;  // (i,c) pair, i=id2/512, c=id2%512
        const int i = id2 >> 9, c = id2 & 511;
        const float scale = bn_g[id2] * rsqrtf(bn_v[id2] + 1e-5f);
        shiftv[id2] = (dw_b[id2] - bn_m[id2]) * scale + bn_b[id2];
        #pragma unroll
        for (int t = 0; t < 9; ++t)
          wT[(i * 9 + t) * DIMC + c] = dw_w[(size_t)id2 * 9 + t] * scale;
      }
    }
    // scaled pointwise bias
    #pragma unroll
    for (int k = 0; k < 1; ++k) {
      if (idx < 3 * DIMC)
        bb[idx] = pw_b[idx] * (idx < DIMC ? QSC : 1.0f);
    }
  }
}

// ---------------------------------------------------------------------------
// Kernel 1 (v2): depthwise 3x3 + folded BN for all 3 projections.
// Thread: 4 output rows x 1 pixel-col x 4 channels x 3 projections.
// 18 independent float4 loads (6 rows x 3 w-positions) -> register window.
// Block: 256 threads = (2 w-columns) x (128 channel-quads).
// Grid: (16 w-pairs, 8 row-groups, 8 batch). All boundary predicates are
// wave-uniform (lanes differ only in channel).
// Output z: [3][B][N][DIM] bf16 bits.
// ---------------------------------------------------------------------------
__global__ __launch_bounds__(256) void dwbn_kernel(
    const float* __restrict__ x, const float* __restrict__ wT,
    const float* __restrict__ shiftv, unsigned short* __restrict__ z) {
  const int wp = blockIdx.x, lg = blockIdx.y, b = blockIdx.z;
  const int t = threadIdx.x;
  const int c = (t & 127) * 4;
  const int w = wp * 2 + (t >> 7);
  const int l0 = lg * 4;
  const float* xb = x + (size_t)b * NPIX * DIMC + c;

  const float4 zero4 = make_float4(0.f, 0.f, 0.f, 0.f);
  float4 win[6][3];
  #pragma unroll
  for (int rr = 0; rr < 6; ++rr) {
    const int l = l0 - 1 + rr;
    #pragma unroll
    for (int dw = 0; dw < 3; ++dw) {
      const int ww = w - 1 + dw;
      const bool ok = ((unsigned)l < IMGS) && ((unsigned)ww < IMGS);
      win[rr][dw] = ok ? *reinterpret_cast<const float4*>(
                             xb + (size_t)(l * IMGS + ww) * DIMC)
                       : zero4;
    }
  }

  #pragma unroll
  for (int i = 0; i < 3; ++i) {
    float4 wv[9];
    #pragma unroll
    for (int tp = 0; tp < 9; ++tp)
      wv[tp] = *reinterpret_cast<const float4*>(wT + (i * 9 + tp) * DIMC + c);
    const float4 sh = *reinterpret_cast<const float4*>(shiftv + i * DIMC + c);
    #pragma unroll
    for (int r = 0; r < 4; ++r) {
      float a0 = sh.x, a1 = sh.y, a2 = sh.z, a3 = sh.w;
      #pragma unroll
      for (int kh = 0; kh < 3; ++kh)
        #pragma unroll
        for (int kw = 0; kw < 3; ++kw) {
          const float4 wq = wv[kh * 3 + kw];
          const float4 xq = win[r + kh][kw];
          a0 = fmaf(wq.x, xq.x, a0);
          a1 = fmaf(wq.y, xq.y, a1);
          a2 = fmaf(wq.z, xq.z, a2);
          a3 = fmaf(wq.w, xq.w, a3);
        }
      ushort4 st;
      st.x = f2b(a0); st.y = f2b(a1); st.z = f2b(a2); st.w = f2b(a3);
      *reinterpret_cast<ushort4*>(
          z + (((size_t)(i * BB + b)) * NPIX + (l0 + r) * IMGS + w) * DIMC + c) = st;
    }
  }
}

// ---------------------------------------------------------------------------
// Kernel 2: MFMA GEMM  C[m][n] = sum_k A[m][k]*W[n][k] + bias[n]
// A bf16 [batch][1024][512], W bf16 [wsel][512][512] (wsel = batch>>3).
// 128x128 tile, BK=32, 4 waves (2x2), 16x16x32 bf16 MFMA, frag-order LDS.
// ---------------------------------------------------------------------------
template <typename CT>
__global__ __launch_bounds__(256) void gemm_mfma(
    const unsigned short* __restrict__ Abase,
    const unsigned short* __restrict__ Wbase,
    const float* __restrict__ biasBase, CT* __restrict__ Cbase) {
  __shared__ short As[8 * 64 * 8];  // 8 KB
  __shared__ short Bs[8 * 64 * 8];  // 8 KB
  const int bz = blockIdx.z;
  const int wi = bz >> 3;
  const short* A = (const short*)Abase + (size_t)bz * NPIX * DIMC;
  const short* W = (const short*)Wbase + (size_t)wi * DIMC * DIMC;
  const float* bias = biasBase + wi * DIMC;
  CT* C = Cbase + (size_t)bz * NPIX * DIMC;

  const int t = threadIdx.x;
  const int wv = t >> 6, lane = t & 63;
  const int lo = lane & 15, hi = lane >> 4;
  const int wm = wv >> 1, wn = wv & 1;
  const int m0 = blockIdx.y * 128, n0 = blockIdx.x * 128;

  float4v acc[4][4];
  #pragma unroll
  for (int i = 0; i < 4; ++i)
    #pragma unroll
    for (int j = 0; j < 4; ++j) acc[i][j] = {0.f, 0.f, 0.f, 0.f};

  for (int k0 = 0; k0 < DIMC; k0 += 32) {
    #pragma unroll
    for (int p = 0; p < 2; ++p) {
      const int sub = wv + p * 4;
      async16(A + (size_t)(m0 + sub * 16 + lo) * DIMC + k0 + hi * 8,
              As + (sub * 64 + lane) * 8);
      async16(W + (size_t)(n0 + sub * 16 + lo) * DIMC + k0 + hi * 8,
              Bs + (sub * 64 + lane) * 8);
    }
    __syncthreads();
    short8 af[4], bf[4];
    #pragma unroll
    for (int mt = 0; mt < 4; ++mt)
      af[mt] = *reinterpret_cast<const short8*>(As + ((wm * 4 + mt) * 64 + lane) * 8);
    #pragma unroll
    for (int nt = 0; nt < 4; ++nt)
      bf[nt] = *reinterpret_cast<const short8*>(Bs + ((wn * 4 + nt) * 64 + lane) * 8);
    #pragma unroll
    for (int mt = 0; mt < 4; ++mt)
      #pragma unroll
      for (int nt = 0; nt < 4; ++nt)
        acc[mt][nt] = __builtin_amdgcn_mfma_f32_16x16x32_bf16(af[mt], bf[nt],
                                                              acc[mt][nt], 0, 0, 0);
    __syncthreads();
  }

  float bv[4];
  #pragma unroll
  for (int nt = 0; nt < 4; ++nt) bv[nt] = bias[n0 + wn * 64 + nt * 16 + lo];
  #pragma unroll
  for (int mt = 0; mt < 4; ++mt) {
    #pragma unroll
    for (int r = 0; r < 4; ++r) {
      const int row = m0 + wm * 64 + mt * 16 + hi * 4 + r;
      CT* cp = C + (size_t)row * DIMC + n0 + wn * 64 + lo;
      #pragma unroll
      for (int nt = 0; nt < 4; ++nt) storeC(cp + nt * 16, acc[mt][nt][r] + bv[nt]);
    }
  }
}

// ---------------------------------------------------------------------------
// Kernel 3: transpose V -> VT[b][h][d(64)][n(1024)] so PV B-frags are
// lane-contiguous. 64x64 LDS tile per block.
// ---------------------------------------------------------------------------
__global__ __launch_bounds__(256) void vt_kernel(
    const unsigned short* __restrict__ v, unsigned short* __restrict__ vt) {
  __shared__ unsigned short tile[64][68];
  const int n0 = blockIdx.x * 64, h = blockIdx.y, b = blockIdx.z;
  const int t = threadIdx.x;
  const unsigned short* vb = v + (size_t)b * NPIX * DIMC + h * DHEAD;
  #pragma unroll
  for (int u = 0; u < 4; ++u) {
    const int lin = t + u * 256;
    const int row = lin >> 4, c4 = (lin & 15) * 4;
    *reinterpret_cast<ushort4*>(&tile[row][c4]) =
        *reinterpret_cast<const ushort4*>(vb + (size_t)(n0 + row) * DIMC + c4);
  }
  __syncthreads();
  unsigned short* vtb = vt + ((size_t)(b * NHEAD + h)) * DHEAD * NPIX;
  #pragma unroll
  for (int u = 0; u < 4; ++u) {
    const int lin = t + u * 256;
    const int d = lin >> 4, n4 = (lin & 15) * 4;
    ushort4 o;
    o.x = tile[n4 + 0][d];
    o.y = tile[n4 + 1][d];
    o.z = tile[n4 + 2][d];
    o.w = tile[n4 + 3][d];
    *reinterpret_cast<ushort4*>(vtb + (size_t)d * NPIX + n0 + n4) = o;
  }
}

// ---------------------------------------------------------------------------
// Kernel 4 (v7): MFMA attention, no-max softmax via exp2 (Q pre-scaled by
// DH^-0.5*log2e in wcvt).
// v6 post-mortem: spills gone (WRITE 8.2MB), XCD swizzle works (FETCH 12MB,
// HBM 5%), but duration unchanged — not memory-bound; MfmaUtil 13% /
// VALUBusy 39% / Occupancy 17% with only 2 blocks/CU resident (LDS 69632
// was the binder). v7 attacks residency: drop the K double-buffer -> LDS
// 53248/block -> 3 blocks/CU (+50% resident waves to fill the serial
// softmax bubbles). Counted pipeline with a SINGLE K buffer:
//   top:  lgkm0 (prior vf/pf reads done) ; issue V(kt)->Vs ;
//         vmcnt(4) = K(kt) landed, V in flight
//   kf <- Ks (4x ds_read_b128) ; lgkm0 (kf in regs) ; issue K(kt+1)->Ks
//         (DMA has exp+PV+next-top ~400cy of slack)
//   QK MFMAs [setprio1] ; exp2/pack/Ps ;
//   vmcnt(4) = V(kt) landed, K(kt+1) in flight ; vf/pf ; PV MFMAs [setprio1]
// Never vmcnt(0) mid-loop. Rolled kt loop — unrolling spills (r1/r2/r4).
// Wave w privately owns k-columns [w*256, w*256+256): NO barriers in K-loop.
// 1-D grid, hb = id&63: same-(b,h) blocks share id%8 -> same XCD L2.
// T5 setprio around MFMA clusters (barrier-free waves = the +4-7% regime).
// Partial O (64x64 f32) and l per wave are reduced across waves at the end.
// ---------------------------------------------------------------------------
__global__ __launch_bounds__(256, 3) void attn_mfma(
    const unsigned short* __restrict__ qkv, const unsigned short* __restrict__ vt,
    unsigned short* __restrict__ attn_o) {
  // per-wave: Ks 4KB | Vs 4KB | Ps 5120B = 13312 B; x4 waves = 53248 B.
  // end-of-kernel overlay: Obuf f32[4*1024] (16KB) | lbuf f32[256] | linv f32[64]
  __shared__ char sm[53248];
  const int hb = blockIdx.x & 63;         // same-(b,h) blocks -> same XCD
  const int qt = blockIdx.x >> 6;
  const int h = hb & 7, b = hb >> 3;
  const int t = threadIdx.x;
  const int wv = t >> 6, lane = t & 63;
  const int lo = lane & 15, hi = lane >> 4;

  char* wbase = sm + wv * 13312;
  short* Ks = (short*)(wbase);
  short* Vs = (short*)(wbase + 4096);
  short* Ps = (short*)(wbase + 8192);  // [64 rows][40] (32 cols + pad 8)

  const short* qb = (const short*)qkv + ((size_t)(0 * BB + b) * NPIX) * DIMC + h * DHEAD;
  const short* kb = (const short*)qkv + ((size_t)(1 * BB + b) * NPIX) * DIMC + h * DHEAD;
  const short* vtb = (const short*)vt + ((size_t)(b * NHEAD + h)) * DHEAD * NPIX;

  // Q A-frags for all 64 q-rows: [mt][cc]
  short8 qf[4][2];
  #pragma unroll
  for (int mt = 0; mt < 4; ++mt)
    #pragma unroll
    for (int cc = 0; cc < 2; ++cc)
      qf[mt][cc] = *reinterpret_cast<const short8*>(
          qb + (size_t)(qt * 64 + mt * 16 + lo) * DIMC + cc * 32 + hi * 8);

  float4v oacc[4][4];
  float4v lsum[4];
  #pragma unroll
  for (int mt = 0; mt < 4; ++mt) {
    lsum[mt] = {0.f, 0.f, 0.f, 0.f};
    #pragma unroll
    for (int dt = 0; dt < 4; ++dt) oacc[mt][dt] = {0.f, 0.f, 0.f, 0.f};
  }

  const int n0 = wv * 256;  // this wave's private k-column strip

  // prologue: stage K tile 0 into Ks (4 DMA ops)
  #pragma unroll
  for (int s = 0; s < 4; ++s) {
    const int nt = s >> 1, cc = s & 1;
    async16(kb + (size_t)(n0 + nt * 16 + lo) * DIMC + cc * 32 + hi * 8,
            Ks + (s * 64 + lane) * 8);
  }

  for (int kt = 0; kt < 8; ++kt) {  // ROLLED — do not unroll (spill hazard)
    const int kbase = n0 + kt * 32;

    // (1) prior PV's vf/pf ds_reads drained -> Vs safe to overwrite
    __builtin_amdgcn_s_waitcnt(WAITCNT_LGKM0);
    __builtin_amdgcn_sched_barrier(0);
    // (2) V(kt) DMA -> Vs (consumed at PV, hidden under QK+exp)
    #pragma unroll
    for (int dt = 0; dt < 4; ++dt)
      async16(vtb + (size_t)(dt * 16 + lo) * NPIX + kbase + hi * 8,
              Vs + (dt * 64 + lane) * 8);
    __builtin_amdgcn_sched_barrier(0);
    // (3) K(kt) landed (issued last iteration); V(kt)'s 4 stay in flight
    __builtin_amdgcn_s_waitcnt(WAITCNT_VM4);
    __builtin_amdgcn_sched_barrier(0);

    // (4) kf <- Ks
    short8 kf[2][2];
    #pragma unroll
    for (int nt = 0; nt < 2; ++nt)
      #pragma unroll
      for (int cc = 0; cc < 2; ++cc)
        kf[nt][cc] = *reinterpret_cast<const short8*>(Ks + ((nt * 2 + cc) * 64 + lane) * 8);
    // (5) kf in regs -> Ks safe to overwrite; issue K(kt+1)
    __builtin_amdgcn_s_waitcnt(WAITCNT_LGKM0);
    __builtin_amdgcn_sched_barrier(0);
    if (kt < 7) {
      #pragma unroll
      for (int s = 0; s < 4; ++s) {
        const int nt = s >> 1, cc = s & 1;
        async16(kb + (size_t)(kbase + 32 + nt * 16 + lo) * DIMC + cc * 32 + hi * 8,
                Ks + (s * 64 + lane) * 8);
      }
    }
    __builtin_amdgcn_sched_barrier(0);

    // (6) S = Q K^T (Q pre-scaled)
    float4v sacc[4][2];
    __builtin_amdgcn_s_setprio(1);
    #pragma unroll
    for (int mt = 0; mt < 4; ++mt)
      #pragma unroll
      for (int nt = 0; nt < 2; ++nt) {
        sacc[mt][nt] = {0.f, 0.f, 0.f, 0.f};
        sacc[mt][nt] = __builtin_amdgcn_mfma_f32_16x16x32_bf16(qf[mt][0], kf[nt][0],
                                                               sacc[mt][nt], 0, 0, 0);
        sacc[mt][nt] = __builtin_amdgcn_mfma_f32_16x16x32_bf16(qf[mt][1], kf[nt][1],
                                                               sacc[mt][nt], 0, 0, 0);
      }
    __builtin_amdgcn_s_setprio(0);

    // (7) p = exp2(s); accumulate l; write P tile
    #pragma unroll
    for (int mt = 0; mt < 4; ++mt)
      #pragma unroll
      for (int nt = 0; nt < 2; ++nt)
        #pragma unroll
        for (int r = 0; r < 4; ++r) {
          const float p = exp2f(sacc[mt][nt][r]);
          Ps[(mt * 16 + hi * 4 + r) * 40 + nt * 16 + lo] = (short)f2b_fast(p);
          lsum[mt][r] += p;
        }

    // (8) V(kt) landed; K(kt+1)'s 4 DMAs remain in flight
    if (kt < 7) {
      __builtin_amdgcn_s_waitcnt(WAITCNT_VM4);
    } else {
      __builtin_amdgcn_s_waitcnt(WAITCNT_VM0);
    }
    __builtin_amdgcn_sched_barrier(0);

    // (9) O += P V   (P A-frags + V B-frags from wave-private LDS)
    short8 vf[4];
    #pragma unroll
    for (int dt = 0; dt < 4; ++dt)
      vf[dt] = *reinterpret_cast<const short8*>(Vs + (dt * 64 + lane) * 8);
    __builtin_amdgcn_s_setprio(1);
    #pragma unroll
    for (int mt = 0; mt < 4; ++mt) {
      const short8 pf = *reinterpret_cast<const short8*>(Ps + (mt * 16 + lo) * 40 + hi * 8);
      #pragma unroll
      for (int dt = 0; dt < 4; ++dt)
        oacc[mt][dt] = __builtin_amdgcn_mfma_f32_16x16x32_bf16(pf, vf[dt],
                                                               oacc[mt][dt], 0, 0, 0);
    }
    __builtin_amdgcn_s_setprio(0);
  }

  // reduce l across the 16 lanes sharing each row
  #pragma unroll
  for (int mt = 0; mt < 4; ++mt)
    #pragma unroll
    for (int r = 0; r < 4; ++r) {
      float v = lsum[mt][r];
      v += __shfl_xor(v, 1);
      v += __shfl_xor(v, 2);
      v += __shfl_xor(v, 4);
      v += __shfl_xor(v, 8);
      lsum[mt][r] = v;
    }

  float* Obuf = (float*)sm;               // 16 KB
  float* lbuf = (float*)(sm + 16384);     // 4*64 f32
  float* linv = (float*)(sm + 17408);     // 64 f32
  __syncthreads();  // all waves done with private LDS
  if (lo == 0) {
    #pragma unroll
    for (int mt = 0; mt < 4; ++mt)
      #pragma unroll
      for (int r = 0; r < 4; ++r) lbuf[wv * 64 + mt * 16 + hi * 4 + r] = lsum[mt][r];
  }
  __syncthreads();
  if (t < 64) linv[t] = 1.0f / (lbuf[t] + lbuf[64 + t] + lbuf[128 + t] + lbuf[192 + t]);

  unsigned short* aob = attn_o + ((size_t)b * NPIX + qt * 64) * DIMC + h * DHEAD;
  #pragma unroll
  for (int mt = 0; mt < 4; ++mt) {
    __syncthreads();
    #pragma unroll
    for (int dt = 0; dt < 4; ++dt)
      #pragma unroll
      for (int r = 0; r < 4; ++r)
        Obuf[wv * 1024 + (dt * 4 + r) * 64 + lane] = oacc[mt][dt][r];
    __syncthreads();
    #pragma unroll
    for (int k2 = 0; k2 < 4; ++k2) {
      const int e = t + k2 * 256;
      const float sum2 = Obuf[e] + Obuf[1024 + e] + Obuf[2048 + e] + Obuf[3072 + e];
      const int dt = e >> 8, r = (e >> 6) & 3, le = e & 63;
      const int row = mt * 16 + (le >> 4) * 4 + r, d = dt * 16 + (le & 15);
      aob[(size_t)row * DIMC + d] = f2b(sum2 * linv[row]);
    }
  }
}

// ---------------------------------------------------------------------------
extern "C" void kernel_launch(void* const* d_in, const int* in_sizes, int n_in,
                              void* d_out, int out_size, void* d_ws, size_t ws_size,
                              hipStream_t stream) {
  const float* x    = (const float*)d_in[0];
  const float* dw_w = (const float*)d_in[1];
  const float* dw_b = (const float*)d_in[2];
  const float* bn_g = (const float*)d_in[3];
  const float* bn_b = (const float*)d_in[4];
  const float* bn_m = (const float*)d_in[5];
  const float* bn_v = (const float*)d_in[6];
  const float* pw_w = (const float*)d_in[7];
  const float* pw_b = (const float*)d_in[8];
  const float* out_w = (const float*)d_in[9];
  const float* out_b = (const float*)d_in[10];
  float* out = (float*)d_out;

  // Workspace layout (bf16 bits as unsigned short):
  //   z      [3][B][N][512]  = 12582912 elems (25.2 MB)
  //   qkv    [3][B][N][512]  = 12582912 elems (25.2 MB)
  //   wbf    pw_w|out_w bf16 =  1048576 elems ( 2.1 MB)
  //   bb     scaled pw_b f32 =  1536
  //   wT     dw tap-major f32 = 3*9*512 = 13824
  //   shiftv folded BN f32   =  1536
  // After the qkv GEMM, z is dead: VT (8.4MB) and attn_o (8.4MB) overlay it.
  unsigned short* z   = (unsigned short*)d_ws;
  unsigned short* qkv = z + (size_t)3 * BB * NPIX * DIMC;
  unsigned short* wbf = qkv + (size_t)3 * BB * NPIX * DIMC;
  float* bb = (float*)(wbf + (size_t)4 * DIMC * DIMC);
  float* wT = bb + 3 * DIMC;
  float* shiftv = wT + 3 * 9 * DIMC;
  unsigned short* vtb = z;
  unsigned short* attn_o = z + (size_t)BB * NHEAD * DHEAD * NPIX;

  wcvt_kernel<<<dim3(1024), 256, 0, stream>>>(pw_w, out_w, pw_b, dw_w, dw_b,
                                              bn_g, bn_b, bn_m, bn_v, wbf, bb,
                                              wT, shiftv);
  dwbn_kernel<<<dim3(16, 8, BB), 256, 0, stream>>>(x, wT, shiftv, z);
  // qkv = z * pw_w^T + bb  (24 batches, W index = batch>>3; q pre-scaled)
  gemm_mfma<unsigned short><<<dim3(4, 8, 24), 256, 0, stream>>>(z, wbf, bb, qkv);
  // VT for PV B-operand
  vt_kernel<<<dim3(16, NHEAD, BB), 256, 0, stream>>>(
      qkv + (size_t)2 * BB * NPIX * DIMC, vtb);
  // attention (1-D grid: hb-major for XCD L2 locality)
  attn_mfma<<<dim3(1024), 256, 0, stream>>>(qkv, vtb, attn_o);
  // out = attn_o * out_w^T + out_b (8 batches, single W at wbf+786432)
  gemm_mfma<float><<<dim3(4, 8, 8), 256, 0, stream>>>(
      attn_o, wbf + (size_t)3 * DIMC * DIMC, out_b, out);
}

// Round 7
// 203.515 us; speedup vs baseline: 1.0421x; 1.0421x over previous
//
#include <hip/hip_runtime.h>
#include <hip/hip_bf16.h>

// Sizes (fixed by the problem)
#define BB    8
#define DIMC  512
#define IMGS  32
#define NPIX  1024   // IMGS*IMGS
#define NHEAD 8
#define DHEAD 64

// Q pre-scale: DH^-0.5 * log2(e).  attn uses exp2 instead of exp, so the
// ln->log2 conversion is folded into the (already folded) 0.125 q scale.
#define QSC 0.18033688011112043f

typedef __attribute__((ext_vector_type(8))) short short8;
typedef __attribute__((ext_vector_type(4))) float float4v;

__device__ __forceinline__ float b2f(unsigned short u) {
  union { unsigned int i; float f; } c;
  c.i = ((unsigned int)u) << 16;
  return c.f;
}
// fp32 -> bf16 bits, round-to-nearest-even
__device__ __forceinline__ unsigned short f2b(float f) {
  union { float f; unsigned int u; } c;
  c.f = f;
  unsigned int r = c.u + 0x7fffu + ((c.u >> 16) & 1u);
  return (unsigned short)(r >> 16);
}
// pack 2 f32 -> 2 bf16 (RNE) in one VALU op (no builtin on gfx950 — inline asm)
__device__ __forceinline__ unsigned int cvt_pk_bf16(float a, float b) {
  unsigned int r;
  asm("v_cvt_pk_bf16_f32 %0, %1, %2" : "=v"(r) : "v"(a), "v"(b));
  return r;
}

__device__ __forceinline__ void storeC(float* p, float v) { *p = v; }
__device__ __forceinline__ void storeC(unsigned short* p, float v) { *p = f2b(v); }

// async global -> LDS, 16 bytes per lane. LDS dest must be wave-uniform base
// + lane*16 (HW constraint) — all call sites below satisfy that.
__device__ __forceinline__ void async16(const void* g, void* l) {
  __builtin_amdgcn_global_load_lds(
      (const __attribute__((address_space(1))) void*)g,
      (__attribute__((address_space(3))) void*)l, 16, 0, 0);
}

// s_waitcnt immediates (gfx9 encoding: vmcnt[3:0]+[15:14], exp[6:4], lgkm[11:8])
#define WAITCNT_VM0   0x0F70   // vmcnt(0), others max
#define WAITCNT_LGKM0 0xC07F   // lgkmcnt(0), others max

// ---------------------------------------------------------------------------
// Kernel 0: weight prep.
//  (a) pw_w (3*512*512) and out_w (512*512) fp32 -> bf16; q block (first
//      512*512) pre-scaled by QSC (=DH^-0.5 * log2e). Scaled bias bb[3*512].
//  (b) depthwise prep: wT[i][tap][512] = dw_w[i][c][tap] * bnscale[i][c],
//      shiftv[i][512] = (dw_b - bn_m)*bnscale + bn_b  (BN folded into conv).
// ---------------------------------------------------------------------------
__global__ __launch_bounds__(256) void wcvt_kernel(
    const float* __restrict__ pw_w, const float* __restrict__ out_w,
    const float* __restrict__ pw_b, const float* __restrict__ dw_w,
    const float* __restrict__ dw_b, const float* __restrict__ bn_g,
    const float* __restrict__ bn_b, const float* __restrict__ bn_m,
    const float* __restrict__ bn_v, unsigned short* __restrict__ wbf,
    float* __restrict__ bb, float* __restrict__ wT,
    float* __restrict__ shiftv) {
  const int i4 = (blockIdx.x * 256 + threadIdx.x) * 4;
  float4 v = (i4 < 3 * DIMC * DIMC)
                 ? *reinterpret_cast<const float4*>(pw_w + i4)
                 : *reinterpret_cast<const float4*>(out_w + (i4 - 3 * DIMC * DIMC));
  const float sc = (i4 < DIMC * DIMC) ? QSC : 1.0f;
  ushort4 o;
  o.x = f2b(v.x * sc); o.y = f2b(v.y * sc); o.z = f2b(v.z * sc); o.w = f2b(v.w * sc);
  *reinterpret_cast<ushort4*>(wbf + i4) = o;
  const int idx = blockIdx.x * 256 + threadIdx.x;
  if (idx < 6 * 256) {
    if (idx < 3 * DIMC / 2) {
      #pragma unroll
      for (int hh = 0; hh < 2; ++hh) {
        const int id2 = idx * 2 + hh;  // (i,c) pair, i=id2/512, c=id2%512
        const int i = id2 >> 9, c = id2 & 511;
        const float scale = bn_g[id2] * rsqrtf(bn_v[id2] + 1e-5f);
        shiftv[id2] = (dw_b[id2] - bn_m[id2]) * scale + bn_b[id2];
        #pragma unroll
        for (int t = 0; t < 9; ++t)
          wT[(i * 9 + t) * DIMC + c] = dw_w[(size_t)id2 * 9 + t] * scale;
      }
    }
    // scaled pointwise bias
    #pragma unroll
    for (int k = 0; k < 1; ++k) {
      if (idx < 3 * DIMC)
        bb[idx] = pw_b[idx] * (idx < DIMC ? QSC : 1.0f);
    }
  }
}

// ---------------------------------------------------------------------------
// Kernel 1 (v2): depthwise 3x3 + folded BN for all 3 projections.
// Thread: 4 output rows x 1 pixel-col x 4 channels x 3 projections.
// 18 independent float4 loads (6 rows x 3 w-positions) -> register window.
// Block: 256 threads = (2 w-columns) x (128 channel-quads).
// Grid: (16 w-pairs, 8 row-groups, 8 batch). All boundary predicates are
// wave-uniform (lanes differ only in channel).
// Output z: [3][B][N][DIM] bf16 bits.
// ---------------------------------------------------------------------------
__global__ __launch_bounds__(256) void dwbn_kernel(
    const float* __restrict__ x, const float* __restrict__ wT,
    const float* __restrict__ shiftv, unsigned short* __restrict__ z) {
  const int wp = blockIdx.x, lg = blockIdx.y, b = blockIdx.z;
  const int t = threadIdx.x;
  const int c = (t & 127) * 4;
  const int w = wp * 2 + (t >> 7);
  const int l0 = lg * 4;
  const float* xb = x + (size_t)b * NPIX * DIMC + c;

  const float4 zero4 = make_float4(0.f, 0.f, 0.f, 0.f);
  float4 win[6][3];
  #pragma unroll
  for (int rr = 0; rr < 6; ++rr) {
    const int l = l0 - 1 + rr;
    #pragma unroll
    for (int dw = 0; dw < 3; ++dw) {
      const int ww = w - 1 + dw;
      const bool ok = ((unsigned)l < IMGS) && ((unsigned)ww < IMGS);
      win[rr][dw] = ok ? *reinterpret_cast<const float4*>(
                             xb + (size_t)(l * IMGS + ww) * DIMC)
                       : zero4;
    }
  }

  #pragma unroll
  for (int i = 0; i < 3; ++i) {
    float4 wv[9];
    #pragma unroll
    for (int tp = 0; tp < 9; ++tp)
      wv[tp] = *reinterpret_cast<const float4*>(wT + (i * 9 + tp) * DIMC + c);
    const float4 sh = *reinterpret_cast<const float4*>(shiftv + i * DIMC + c);
    #pragma unroll
    for (int r = 0; r < 4; ++r) {
      float a0 = sh.x, a1 = sh.y, a2 = sh.z, a3 = sh.w;
      #pragma unroll
      for (int kh = 0; kh < 3; ++kh)
        #pragma unroll
        for (int kw = 0; kw < 3; ++kw) {
          const float4 wq = wv[kh * 3 + kw];
          const float4 xq = win[r + kh][kw];
          a0 = fmaf(wq.x, xq.x, a0);
          a1 = fmaf(wq.y, xq.y, a1);
          a2 = fmaf(wq.z, xq.z, a2);
          a3 = fmaf(wq.w, xq.w, a3);
        }
      ushort4 st;
      st.x = f2b(a0); st.y = f2b(a1); st.z = f2b(a2); st.w = f2b(a3);
      *reinterpret_cast<ushort4*>(
          z + (((size_t)(i * BB + b)) * NPIX + (l0 + r) * IMGS + w) * DIMC + c) = st;
    }
  }
}

// ---------------------------------------------------------------------------
// Kernel 2: MFMA GEMM  C[m][n] = sum_k A[m][k]*W[n][k] + bias[n]
// A bf16 [batch][1024][512], W bf16 [wsel][512][512] (wsel = batch>>3).
// 128x128 tile, BK=32, 4 waves (2x2), 16x16x32 bf16 MFMA, frag-order LDS.
// ---------------------------------------------------------------------------
template <typename CT>
__global__ __launch_bounds__(256) void gemm_mfma(
    const unsigned short* __restrict__ Abase,
    const unsigned short* __restrict__ Wbase,
    const float* __restrict__ biasBase, CT* __restrict__ Cbase) {
  __shared__ short As[8 * 64 * 8];  // 8 KB
  __shared__ short Bs[8 * 64 * 8];  // 8 KB
  const int bz = blockIdx.z;
  const int wi = bz >> 3;
  const short* A = (const short*)Abase + (size_t)bz * NPIX * DIMC;
  const short* W = (const short*)Wbase + (size_t)wi * DIMC * DIMC;
  const float* bias = biasBase + wi * DIMC;
  CT* C = Cbase + (size_t)bz * NPIX * DIMC;

  const int t = threadIdx.x;
  const int wv = t >> 6, lane = t & 63;
  const int lo = lane & 15, hi = lane >> 4;
  const int wm = wv >> 1, wn = wv & 1;
  const int m0 = blockIdx.y * 128, n0 = blockIdx.x * 128;

  float4v acc[4][4];
  #pragma unroll
  for (int i = 0; i < 4; ++i)
    #pragma unroll
    for (int j = 0; j < 4; ++j) acc[i][j] = {0.f, 0.f, 0.f, 0.f};

  for (int k0 = 0; k0 < DIMC; k0 += 32) {
    #pragma unroll
    for (int p = 0; p < 2; ++p) {
      const int sub = wv + p * 4;
      async16(A + (size_t)(m0 + sub * 16 + lo) * DIMC + k0 + hi * 8,
              As + (sub * 64 + lane) * 8);
      async16(W + (size_t)(n0 + sub * 16 + lo) * DIMC + k0 + hi * 8,
              Bs + (sub * 64 + lane) * 8);
    }
    __syncthreads();
    short8 af[4], bf[4];
    #pragma unroll
    for (int mt = 0; mt < 4; ++mt)
      af[mt] = *reinterpret_cast<const short8*>(As + ((wm * 4 + mt) * 64 + lane) * 8);
    #pragma unroll
    for (int nt = 0; nt < 4; ++nt)
      bf[nt] = *reinterpret_cast<const short8*>(Bs + ((wn * 4 + nt) * 64 + lane) * 8);
    #pragma unroll
    for (int mt = 0; mt < 4; ++mt)
      #pragma unroll
      for (int nt = 0; nt < 4; ++nt)
        acc[mt][nt] = __builtin_amdgcn_mfma_f32_16x16x32_bf16(af[mt], bf[nt],
                                                              acc[mt][nt], 0, 0, 0);
    __syncthreads();
  }

  float bv[4];
  #pragma unroll
  for (int nt = 0; nt < 4; ++nt) bv[nt] = bias[n0 + wn * 64 + nt * 16 + lo];
  #pragma unroll
  for (int mt = 0; mt < 4; ++mt) {
    #pragma unroll
    for (int r = 0; r < 4; ++r) {
      const int row = m0 + wm * 64 + mt * 16 + hi * 4 + r;
      CT* cp = C + (size_t)row * DIMC + n0 + wn * 64 + lo;
      #pragma unroll
      for (int nt = 0; nt < 4; ++nt) storeC(cp + nt * 16, acc[mt][nt][r] + bv[nt]);
    }
  }
}

// ---------------------------------------------------------------------------
// Kernel 3: transpose V -> VT[b][h][d(64)][n(1024)] so PV B-frags are
// lane-contiguous. 64x64 LDS tile per block.
// ---------------------------------------------------------------------------
__global__ __launch_bounds__(256) void vt_kernel(
    const unsigned short* __restrict__ v, unsigned short* __restrict__ vt) {
  __shared__ unsigned short tile[64][68];
  const int n0 = blockIdx.x * 64, h = blockIdx.y, b = blockIdx.z;
  const int t = threadIdx.x;
  const unsigned short* vb = v + (size_t)b * NPIX * DIMC + h * DHEAD;
  #pragma unroll
  for (int u = 0; u < 4; ++u) {
    const int lin = t + u * 256;
    const int row = lin >> 4, c4 = (lin & 15) * 4;
    *reinterpret_cast<ushort4*>(&tile[row][c4]) =
        *reinterpret_cast<const ushort4*>(vb + (size_t)(n0 + row) * DIMC + c4);
  }
  __syncthreads();
  unsigned short* vtb = vt + ((size_t)(b * NHEAD + h)) * DHEAD * NPIX;
  #pragma unroll
  for (int u = 0; u < 4; ++u) {
    const int lin = t + u * 256;
    const int d = lin >> 4, n4 = (lin & 15) * 4;
    ushort4 o;
    o.x = tile[n4 + 0][d];
    o.y = tile[n4 + 1][d];
    o.z = tile[n4 + 2][d];
    o.w = tile[n4 + 3][d];
    *reinterpret_cast<ushort4*>(vtb + (size_t)d * NPIX + n0 + n4) = o;
  }
}

// ---------------------------------------------------------------------------
// Kernel 4 (v8): MFMA attention, no-max softmax via exp2 (Q pre-scaled by
// DH^-0.5*log2e in wcvt).
// Staging schedule = round-0's proven one (stage K,V -> vmcnt(0) -> compute;
// r4-r6 proved schedule choreography is NOT the lever — r0's 47.7us stood).
// The change here is the SOFTMAX DATA PATH (the largest reducible serial
// component: ~500 VALU ops/tile, 32 scalar ds_write_b16 + per-element addr
// arithmetic):
//   * QK^T computed OPERAND-SWAPPED: mfma(kf, qf) -> S[k'][q] with
//     q = mt*16+lo (lane-fixed), k' = nt*16+hi*4+r (consecutive in r).
//   * P-store packed: 2x v_cvt_pk_bf16_f32 (RNE) + 1 ds_write_b64 per
//     (mt,nt) — 8 b64 writes/tile vs 32 b16 + 64 pack ops; write address is
//     per-lane base + compile-time immediate (addr VALU eliminated).
//   * Ps layout [64 q][40] row-major UNCHANGED -> PV pf ds_read_b128 path
//     is byte-identical to the proven one.
//   * lsum: one scalar per mt (fixed q per lane); l-reduce = shfl_xor 16,32.
// LDS 13312/wave (Ks 4K | VTs 4K | Ps 5120) x4 = 53248 -> 3 blocks/CU
// (launch_bounds (256,3); r6 proved 3 fit — its regression was its schedule).
// Wave w privately owns k-columns [w*256, w*256+256): NO barriers in K-loop.
// 1-D grid, hb = id&63: same-(b,h) blocks share id%8 -> same XCD L2
// (FETCH 70MB -> 12MB, proven r5).
// Partial O (64x64 f32) and l per wave are reduced across waves at the end.
// ---------------------------------------------------------------------------
__global__ __launch_bounds__(256, 3) void attn_mfma(
    const unsigned short* __restrict__ qkv, const unsigned short* __restrict__ vt,
    unsigned short* __restrict__ attn_o) {
  // per-wave: Ks 4KB | VTs 4KB | Ps 5120B = 13312 B; x4 waves = 53248 B.
  // end-of-kernel overlay: Obuf f32[4*1024] (16KB) | lbuf f32[256] | linv f32[64]
  __shared__ char sm[53248];
  const int hb = blockIdx.x & 63;         // same-(b,h) blocks -> same XCD
  const int qt = blockIdx.x >> 6;
  const int h = hb & 7, b = hb >> 3;
  const int t = threadIdx.x;
  const int wv = t >> 6, lane = t & 63;
  const int lo = lane & 15, hi = lane >> 4;

  char* wbase = sm + wv * 13312;
  short* Ks  = (short*)(wbase);
  short* VTs = (short*)(wbase + 4096);
  short* Ps  = (short*)(wbase + 8192);  // [64 q-rows][40] (32 k-cols + pad 8)

  const short* qb = (const short*)qkv + ((size_t)(0 * BB + b) * NPIX) * DIMC + h * DHEAD;
  const short* kb = (const short*)qkv + ((size_t)(1 * BB + b) * NPIX) * DIMC + h * DHEAD;
  const short* vtb = (const short*)vt + ((size_t)(b * NHEAD + h)) * DHEAD * NPIX;

  // Q A-frags for all 64 q-rows: [mt][cc]
  short8 qf[4][2];
  #pragma unroll
  for (int mt = 0; mt < 4; ++mt)
    #pragma unroll
    for (int cc = 0; cc < 2; ++cc)
      qf[mt][cc] = *reinterpret_cast<const short8*>(
          qb + (size_t)(qt * 64 + mt * 16 + lo) * DIMC + cc * 32 + hi * 8);

  float4v oacc[4][4];
  float lsum[4];
  #pragma unroll
  for (int mt = 0; mt < 4; ++mt) {
    lsum[mt] = 0.f;
    #pragma unroll
    for (int dt = 0; dt < 4; ++dt) oacc[mt][dt] = {0.f, 0.f, 0.f, 0.f};
  }

  const int n0 = wv * 256;  // this wave's private k-column strip
  // per-lane Ps write base (shorts); per-(mt,nt) offset is a compile-time imm
  short* PsW = Ps + lo * 40 + hi * 4;

  for (int kt = 0; kt < 8; ++kt) {  // ROLLED — do not unroll (spill hazard)
    const int kbase = n0 + kt * 32;
    // prior tile's ds_reads must drain before LDS is overwritten
    __builtin_amdgcn_s_waitcnt(WAITCNT_LGKM0);
    __builtin_amdgcn_sched_barrier(0);
    #pragma unroll
    for (int s = 0; s < 4; ++s) {
      const int nt = s >> 1, cc = s & 1;
      async16(kb + (size_t)(kbase + nt * 16 + lo) * DIMC + cc * 32 + hi * 8,
              Ks + (s * 64 + lane) * 8);
    }
    #pragma unroll
    for (int dt = 0; dt < 4; ++dt)
      async16(vtb + (size_t)(dt * 16 + lo) * NPIX + kbase + hi * 8,
              VTs + (dt * 64 + lane) * 8);
    __builtin_amdgcn_sched_barrier(0);
    __builtin_amdgcn_s_waitcnt(WAITCNT_VM0);
    __builtin_amdgcn_sched_barrier(0);

    // S^T = K Q^T (operand-swapped): sacc[mt][nt] reg r =
    //   S[k' = nt*16 + hi*4 + r][q = mt*16 + lo]
    short8 kf[2][2];
    #pragma unroll
    for (int nt = 0; nt < 2; ++nt)
      #pragma unroll
      for (int cc = 0; cc < 2; ++cc)
        kf[nt][cc] = *reinterpret_cast<const short8*>(Ks + ((nt * 2 + cc) * 64 + lane) * 8);
    float4v sacc[4][2];
    #pragma unroll
    for (int mt = 0; mt < 4; ++mt)
      #pragma unroll
      for (int nt = 0; nt < 2; ++nt) {
        sacc[mt][nt] = {0.f, 0.f, 0.f, 0.f};
        sacc[mt][nt] = __builtin_amdgcn_mfma_f32_16x16x32_bf16(kf[nt][0], qf[mt][0],
                                                               sacc[mt][nt], 0, 0, 0);
        sacc[mt][nt] = __builtin_amdgcn_mfma_f32_16x16x32_bf16(kf[nt][1], qf[mt][1],
                                                               sacc[mt][nt], 0, 0, 0);
      }

    // p = exp2(s); pack pairs (RNE) and store 4 k-cols of row q per b64.
    // Row q = mt*16+lo; cols nt*16+hi*4 .. +3 — consecutive in r.
    #pragma unroll
    for (int mt = 0; mt < 4; ++mt) {
      const float p00 = exp2f(sacc[mt][0][0]);
      const float p01 = exp2f(sacc[mt][0][1]);
      const float p02 = exp2f(sacc[mt][0][2]);
      const float p03 = exp2f(sacc[mt][0][3]);
      const float p10 = exp2f(sacc[mt][1][0]);
      const float p11 = exp2f(sacc[mt][1][1]);
      const float p12 = exp2f(sacc[mt][1][2]);
      const float p13 = exp2f(sacc[mt][1][3]);
      uint2 w0, w1;
      w0.x = cvt_pk_bf16(p00, p01); w0.y = cvt_pk_bf16(p02, p03);
      w1.x = cvt_pk_bf16(p10, p11); w1.y = cvt_pk_bf16(p12, p13);
      *reinterpret_cast<uint2*>(PsW + mt * 640) = w0;        // nt=0
      *reinterpret_cast<uint2*>(PsW + mt * 640 + 16) = w1;   // nt=1
      lsum[mt] += ((p00 + p01) + (p02 + p03)) + ((p10 + p11) + (p12 + p13));
    }

    // O += P V   (P A-frags from wave-private LDS — read path unchanged;
    //             VT B-frags frag-order)
    short8 vf[4];
    #pragma unroll
    for (int dt = 0; dt < 4; ++dt)
      vf[dt] = *reinterpret_cast<const short8*>(VTs + (dt * 64 + lane) * 8);
    #pragma unroll
    for (int mt = 0; mt < 4; ++mt) {
      const short8 pf = *reinterpret_cast<const short8*>(Ps + (mt * 16 + lo) * 40 + hi * 8);
      #pragma unroll
      for (int dt = 0; dt < 4; ++dt)
        oacc[mt][dt] = __builtin_amdgcn_mfma_f32_16x16x32_bf16(pf, vf[dt],
                                                               oacc[mt][dt], 0, 0, 0);
    }
  }

  // reduce l across the 4 hi-groups sharing each q (= lo) row
  float lv[4];
  #pragma unroll
  for (int mt = 0; mt < 4; ++mt) {
    float v = lsum[mt];
    v += __shfl_xor(v, 16);
    v += __shfl_xor(v, 32);
    lv[mt] = v;
  }

  float* Obuf = (float*)sm;               // 16 KB
  float* lbuf = (float*)(sm + 16384);     // 4*64 f32
  float* linv = (float*)(sm + 17408);     // 64 f32
  __syncthreads();  // all waves done with private LDS
  if (hi == 0) {
    #pragma unroll
    for (int mt = 0; mt < 4; ++mt) lbuf[wv * 64 + mt * 16 + lo] = lv[mt];
  }
  __syncthreads();
  if (t < 64) linv[t] = 1.0f / (lbuf[t] + lbuf[64 + t] + lbuf[128 + t] + lbuf[192 + t]);

  unsigned short* aob = attn_o + ((size_t)b * NPIX + qt * 64) * DIMC + h * DHEAD;
  #pragma unroll
  for (int mt = 0; mt < 4; ++mt) {
    __syncthreads();
    #pragma unroll
    for (int dt = 0; dt < 4; ++dt)
      #pragma unroll
      for (int r = 0; r < 4; ++r)
        Obuf[wv * 1024 + (dt * 4 + r) * 64 + lane] = oacc[mt][dt][r];
    __syncthreads();
    #pragma unroll
    for (int k2 = 0; k2 < 4; ++k2) {
      const int e = t + k2 * 256;
      const float sum2 = Obuf[e] + Obuf[1024 + e] + Obuf[2048 + e] + Obuf[3072 + e];
      const int dt = e >> 8, r = (e >> 6) & 3, le = e & 63;
      const int row = mt * 16 + (le >> 4) * 4 + r, d = dt * 16 + (le & 15);
      aob[(size_t)row * DIMC + d] = f2b(sum2 * linv[row]);
    }
  }
}

// ---------------------------------------------------------------------------
extern "C" void kernel_launch(void* const* d_in, const int* in_sizes, int n_in,
                              void* d_out, int out_size, void* d_ws, size_t ws_size,
                              hipStream_t stream) {
  const float* x    = (const float*)d_in[0];
  const float* dw_w = (const float*)d_in[1];
  const float* dw_b = (const float*)d_in[2];
  const float* bn_g = (const float*)d_in[3];
  const float* bn_b = (const float*)d_in[4];
  const float* bn_m = (const float*)d_in[5];
  const float* bn_v = (const float*)d_in[6];
  const float* pw_w = (const float*)d_in[7];
  const float* pw_b = (const float*)d_in[8];
  const float* out_w = (const float*)d_in[9];
  const float* out_b = (const float*)d_in[10];
  float* out = (float*)d_out;

  // Workspace layout (bf16 bits as unsigned short):
  //   z      [3][B][N][512]  = 12582912 elems (25.2 MB)
  //   qkv    [3][B][N][512]  = 12582912 elems (25.2 MB)
  //   wbf    pw_w|out_w bf16 =  1048576 elems ( 2.1 MB)
  //   bb     scaled pw_b f32 =  1536
  //   wT     dw tap-major f32 = 3*9*512 = 13824
  //   shiftv folded BN f32   =  1536
  // After the qkv GEMM, z is dead: VT (8.4MB) and attn_o (8.4MB) overlay it.
  unsigned short* z   = (unsigned short*)d_ws;
  unsigned short* qkv = z + (size_t)3 * BB * NPIX * DIMC;
  unsigned short* wbf = qkv + (size_t)3 * BB * NPIX * DIMC;
  float* bb = (float*)(wbf + (size_t)4 * DIMC * DIMC);
  float* wT = bb + 3 * DIMC;
  float* shiftv = wT + 3 * 9 * DIMC;
  unsigned short* vtb = z;
  unsigned short* attn_o = z + (size_t)BB * NHEAD * DHEAD * NPIX;

  wcvt_kernel<<<dim3(1024), 256, 0, stream>>>(pw_w, out_w, pw_b, dw_w, dw_b,
                                              bn_g, bn_b, bn_m, bn_v, wbf, bb,
                                              wT, shiftv);
  dwbn_kernel<<<dim3(16, 8, BB), 256, 0, stream>>>(x, wT, shiftv, z);
  // qkv = z * pw_w^T + bb  (24 batches, W index = batch>>3; q pre-scaled)
  gemm_mfma<unsigned short><<<dim3(4, 8, 24), 256, 0, stream>>>(z, wbf, bb, qkv);
  // VT for PV B-operand
  vt_kernel<<<dim3(16, NHEAD, BB), 256, 0, stream>>>(
      qkv + (size_t)2 * BB * NPIX * DIMC, vtb);
  // attention (1-D grid: hb-major for XCD L2 locality)
  attn_mfma<<<dim3(1024), 256, 0, stream>>>(qkv, vtb, attn_o);
  // out = attn_o * out_w^T + out_b (8 batches, single W at wbf+786432)
  gemm_mfma<float><<<dim3(4, 8, 8), 256, 0, stream>>>(
      attn_o, wbf + (size_t)3 * DIMC * DIMC, out_b, out);
}

// Round 8
// 201.482 us; speedup vs baseline: 1.0526x; 1.0101x over previous
//
#include <hip/hip_runtime.h>
#include <hip/hip_bf16.h>

// Sizes (fixed by the problem)
#define BB    8
#define DIMC  512
#define IMGS  32
#define NPIX  1024   // IMGS*IMGS
#define NHEAD 8
#define DHEAD 64

// Q pre-scale: DH^-0.5. attn uses __expf (v_mul+v_exp_f32, 2 VALU ops — the
// FAST path; exp2f is the precise libm path, ~10+ ops/call, measured r5-r7
// as +7pts VALUBusy on the critical chain).
#define QSC 0.125f

typedef __attribute__((ext_vector_type(8))) short short8;
typedef __attribute__((ext_vector_type(4))) float float4v;

__device__ __forceinline__ float b2f(unsigned short u) {
  union { unsigned int i; float f; } c;
  c.i = ((unsigned int)u) << 16;
  return c.f;
}
// fp32 -> bf16 bits, round-to-nearest-even
__device__ __forceinline__ unsigned short f2b(float f) {
  union { float f; unsigned int u; } c;
  c.f = f;
  unsigned int r = c.u + 0x7fffu + ((c.u >> 16) & 1u);
  return (unsigned short)(r >> 16);
}
// pack 2 f32 -> 2 bf16 (RNE) in one VALU op (no builtin on gfx950 — inline asm)
__device__ __forceinline__ unsigned int cvt_pk_bf16(float a, float b) {
  unsigned int r;
  asm("v_cvt_pk_bf16_f32 %0, %1, %2" : "=v"(r) : "v"(a), "v"(b));
  return r;
}

__device__ __forceinline__ void storeC(float* p, float v) { *p = v; }
__device__ __forceinline__ void storeC(unsigned short* p, float v) { *p = f2b(v); }

// async global -> LDS, 16 bytes per lane. LDS dest must be wave-uniform base
// + lane*16 (HW constraint) — all call sites below satisfy that.
__device__ __forceinline__ void async16(const void* g, void* l) {
  __builtin_amdgcn_global_load_lds(
      (const __attribute__((address_space(1))) void*)g,
      (__attribute__((address_space(3))) void*)l, 16, 0, 0);
}

// s_waitcnt immediates (gfx9 encoding: vmcnt[3:0]+[15:14], exp[6:4], lgkm[11:8])
#define WAITCNT_VM0   0x0F70   // vmcnt(0), others max
#define WAITCNT_LGKM0 0xC07F   // lgkmcnt(0), others max

// ---------------------------------------------------------------------------
// Kernel 0: weight prep.
//  (a) pw_w (3*512*512) and out_w (512*512) fp32 -> bf16; q block (first
//      512*512) pre-scaled by QSC (=DH^-0.5). Scaled bias bb[3*512].
//  (b) depthwise prep: wT[i][tap][512] = dw_w[i][c][tap] * bnscale[i][c],
//      shiftv[i][512] = (dw_b - bn_m)*bnscale + bn_b  (BN folded into conv).
// ---------------------------------------------------------------------------
__global__ __launch_bounds__(256) void wcvt_kernel(
    const float* __restrict__ pw_w, const float* __restrict__ out_w,
    const float* __restrict__ pw_b, const float* __restrict__ dw_w,
    const float* __restrict__ dw_b, const float* __restrict__ bn_g,
    const float* __restrict__ bn_b, const float* __restrict__ bn_m,
    const float* __restrict__ bn_v, unsigned short* __restrict__ wbf,
    float* __restrict__ bb, float* __restrict__ wT,
    float* __restrict__ shiftv) {
  const int i4 = (blockIdx.x * 256 + threadIdx.x) * 4;
  float4 v = (i4 < 3 * DIMC * DIMC)
                 ? *reinterpret_cast<const float4*>(pw_w + i4)
                 : *reinterpret_cast<const float4*>(out_w + (i4 - 3 * DIMC * DIMC));
  const float sc = (i4 < DIMC * DIMC) ? QSC : 1.0f;
  ushort4 o;
  o.x = f2b(v.x * sc); o.y = f2b(v.y * sc); o.z = f2b(v.z * sc); o.w = f2b(v.w * sc);
  *reinterpret_cast<ushort4*>(wbf + i4) = o;
  const int idx = blockIdx.x * 256 + threadIdx.x;
  if (idx < 6 * 256) {
    if (idx < 3 * DIMC / 2) {
      #pragma unroll
      for (int hh = 0; hh < 2; ++hh) {
        const int id2 = idx * 2 + hh;  // (i,c) pair, i=id2/512, c=id2%512
        const int i = id2 >> 9, c = id2 & 511;
        const float scale = bn_g[id2] * rsqrtf(bn_v[id2] + 1e-5f);
        shiftv[id2] = (dw_b[id2] - bn_m[id2]) * scale + bn_b[id2];
        #pragma unroll
        for (int t = 0; t < 9; ++t)
          wT[(i * 9 + t) * DIMC + c] = dw_w[(size_t)id2 * 9 + t] * scale;
      }
    }
    // scaled pointwise bias
    #pragma unroll
    for (int k = 0; k < 1; ++k) {
      if (idx < 3 * DIMC)
        bb[idx] = pw_b[idx] * (idx < DIMC ? QSC : 1.0f);
    }
  }
}

// ---------------------------------------------------------------------------
// Kernel 1 (v2): depthwise 3x3 + folded BN for all 3 projections.
// Thread: 4 output rows x 1 pixel-col x 4 channels x 3 projections.
// 18 independent float4 loads (6 rows x 3 w-positions) -> register window.
// Block: 256 threads = (2 w-columns) x (128 channel-quads).
// Grid: (16 w-pairs, 8 row-groups, 8 batch). All boundary predicates are
// wave-uniform (lanes differ only in channel).
// Output z: [3][B][N][DIM] bf16 bits.
// ---------------------------------------------------------------------------
__global__ __launch_bounds__(256) void dwbn_kernel(
    const float* __restrict__ x, const float* __restrict__ wT,
    const float* __restrict__ shiftv, unsigned short* __restrict__ z) {
  const int wp = blockIdx.x, lg = blockIdx.y, b = blockIdx.z;
  const int t = threadIdx.x;
  const int c = (t & 127) * 4;
  const int w = wp * 2 + (t >> 7);
  const int l0 = lg * 4;
  const float* xb = x + (size_t)b * NPIX * DIMC + c;

  const float4 zero4 = make_float4(0.f, 0.f, 0.f, 0.f);
  float4 win[6][3];
  #pragma unroll
  for (int rr = 0; rr < 6; ++rr) {
    const int l = l0 - 1 + rr;
    #pragma unroll
    for (int dw = 0; dw < 3; ++dw) {
      const int ww = w - 1 + dw;
      const bool ok = ((unsigned)l < IMGS) && ((unsigned)ww < IMGS);
      win[rr][dw] = ok ? *reinterpret_cast<const float4*>(
                             xb + (size_t)(l * IMGS + ww) * DIMC)
                       : zero4;
    }
  }

  #pragma unroll
  for (int i = 0; i < 3; ++i) {
    float4 wv[9];
    #pragma unroll
    for (int tp = 0; tp < 9; ++tp)
      wv[tp] = *reinterpret_cast<const float4*>(wT + (i * 9 + tp) * DIMC + c);
    const float4 sh = *reinterpret_cast<const float4*>(shiftv + i * DIMC + c);
    #pragma unroll
    for (int r = 0; r < 4; ++r) {
      float a0 = sh.x, a1 = sh.y, a2 = sh.z, a3 = sh.w;
      #pragma unroll
      for (int kh = 0; kh < 3; ++kh)
        #pragma unroll
        for (int kw = 0; kw < 3; ++kw) {
          const float4 wq = wv[kh * 3 + kw];
          const float4 xq = win[r + kh][kw];
          a0 = fmaf(wq.x, xq.x, a0);
          a1 = fmaf(wq.y, xq.y, a1);
          a2 = fmaf(wq.z, xq.z, a2);
          a3 = fmaf(wq.w, xq.w, a3);
        }
      ushort4 st;
      st.x = f2b(a0); st.y = f2b(a1); st.z = f2b(a2); st.w = f2b(a3);
      *reinterpret_cast<ushort4*>(
          z + (((size_t)(i * BB + b)) * NPIX + (l0 + r) * IMGS + w) * DIMC + c) = st;
    }
  }
}

// ---------------------------------------------------------------------------
// Kernel 2: MFMA GEMM  C[m][n] = sum_k A[m][k]*W[n][k] + bias[n]
// A bf16 [batch][1024][512], W bf16 [wsel][512][512] (wsel = batch>>3).
// 128x128 tile, BK=32, 4 waves (2x2), 16x16x32 bf16 MFMA, frag-order LDS.
// XCD-chunked 1-D grid (T1): id&7 selects the XCD (HW round-robin on
// dispatch id); each XCD gets NBATCH/8 whole batches -> A+W panels stay in
// its private L2 (attn's swizzle measured FETCH 70->12MB on this workload).
// bz = (id&7)*(NBATCH/8) + (id>>3)/32 ; within = (id>>3)&31 (bijective).
// ---------------------------------------------------------------------------
template <typename CT, int NBATCH>
__global__ __launch_bounds__(256) void gemm_mfma(
    const unsigned short* __restrict__ Abase,
    const unsigned short* __restrict__ Wbase,
    const float* __restrict__ biasBase, CT* __restrict__ Cbase) {
  __shared__ short As[8 * 64 * 8];  // 8 KB
  __shared__ short Bs[8 * 64 * 8];  // 8 KB
  const int id = blockIdx.x;
  const int bz = (id & 7) * (NBATCH / 8) + ((id >> 3) >> 5);
  const int within = (id >> 3) & 31;
  const int wi = bz >> 3;
  const short* A = (const short*)Abase + (size_t)bz * NPIX * DIMC;
  const short* W = (const short*)Wbase + (size_t)wi * DIMC * DIMC;
  const float* bias = biasBase + wi * DIMC;
  CT* C = Cbase + (size_t)bz * NPIX * DIMC;

  const int t = threadIdx.x;
  const int wv = t >> 6, lane = t & 63;
  const int lo = lane & 15, hi = lane >> 4;
  const int wm = wv >> 1, wn = wv & 1;
  const int m0 = (within >> 2) * 128, n0 = (within & 3) * 128;

  float4v acc[4][4];
  #pragma unroll
  for (int i = 0; i < 4; ++i)
    #pragma unroll
    for (int j = 0; j < 4; ++j) acc[i][j] = {0.f, 0.f, 0.f, 0.f};

  for (int k0 = 0; k0 < DIMC; k0 += 32) {
    #pragma unroll
    for (int p = 0; p < 2; ++p) {
      const int sub = wv + p * 4;
      async16(A + (size_t)(m0 + sub * 16 + lo) * DIMC + k0 + hi * 8,
              As + (sub * 64 + lane) * 8);
      async16(W + (size_t)(n0 + sub * 16 + lo) * DIMC + k0 + hi * 8,
              Bs + (sub * 64 + lane) * 8);
    }
    __syncthreads();
    short8 af[4], bf[4];
    #pragma unroll
    for (int mt = 0; mt < 4; ++mt)
      af[mt] = *reinterpret_cast<const short8*>(As + ((wm * 4 + mt) * 64 + lane) * 8);
    #pragma unroll
    for (int nt = 0; nt < 4; ++nt)
      bf[nt] = *reinterpret_cast<const short8*>(Bs + ((wn * 4 + nt) * 64 + lane) * 8);
    #pragma unroll
    for (int mt = 0; mt < 4; ++mt)
      #pragma unroll
      for (int nt = 0; nt < 4; ++nt)
        acc[mt][nt] = __builtin_amdgcn_mfma_f32_16x16x32_bf16(af[mt], bf[nt],
                                                              acc[mt][nt], 0, 0, 0);
    __syncthreads();
  }

  float bv[4];
  #pragma unroll
  for (int nt = 0; nt < 4; ++nt) bv[nt] = bias[n0 + wn * 64 + nt * 16 + lo];
  #pragma unroll
  for (int mt = 0; mt < 4; ++mt) {
    #pragma unroll
    for (int r = 0; r < 4; ++r) {
      const int row = m0 + wm * 64 + mt * 16 + hi * 4 + r;
      CT* cp = C + (size_t)row * DIMC + n0 + wn * 64 + lo;
      #pragma unroll
      for (int nt = 0; nt < 4; ++nt) storeC(cp + nt * 16, acc[mt][nt][r] + bv[nt]);
    }
  }
}

// ---------------------------------------------------------------------------
// Kernel 3: transpose V -> VT[b][h][d(64)][n(1024)] so PV B-frags are
// lane-contiguous. 64x64 LDS tile per block.
// ---------------------------------------------------------------------------
__global__ __launch_bounds__(256) void vt_kernel(
    const unsigned short* __restrict__ v, unsigned short* __restrict__ vt) {
  __shared__ unsigned short tile[64][68];
  const int n0 = blockIdx.x * 64, h = blockIdx.y, b = blockIdx.z;
  const int t = threadIdx.x;
  const unsigned short* vb = v + (size_t)b * NPIX * DIMC + h * DHEAD;
  #pragma unroll
  for (int u = 0; u < 4; ++u) {
    const int lin = t + u * 256;
    const int row = lin >> 4, c4 = (lin & 15) * 4;
    *reinterpret_cast<ushort4*>(&tile[row][c4]) =
        *reinterpret_cast<const ushort4*>(vb + (size_t)(n0 + row) * DIMC + c4);
  }
  __syncthreads();
  unsigned short* vtb = vt + ((size_t)(b * NHEAD + h)) * DHEAD * NPIX;
  #pragma unroll
  for (int u = 0; u < 4; ++u) {
    const int lin = t + u * 256;
    const int d = lin >> 4, n4 = (lin & 15) * 4;
    ushort4 o;
    o.x = tile[n4 + 0][d];
    o.y = tile[n4 + 1][d];
    o.z = tile[n4 + 2][d];
    o.w = tile[n4 + 3][d];
    *reinterpret_cast<ushort4*>(vtb + (size_t)d * NPIX + n0 + n4) = o;
  }
}

// ---------------------------------------------------------------------------
// Kernel 4 (v9): MFMA attention, no-max softmax via __expf (Q pre-scaled by
// DH^-0.5 in wcvt; __expf = v_mul+v_exp_f32 fast path — exp2f was the
// precise libm path and cost +7pts VALUBusy on the critical chain, r5-r7).
// Keeps r7's softmax data path (the proven-mechanical part):
//   * QK^T operand-swapped: mfma(kf, qf) -> S[k'][q], q=mt*16+lo lane-fixed.
//   * P-store packed: cvt_pk_bf16 pairs + ds_write_b64, per-lane base +
//     compile-time immediate; Ps [64 q][40] row-major so the PV pf
//     ds_read_b128 path is unchanged.
//   * lsum scalar per mt; l-reduce = shfl_xor 16,32.
// Staging = round-0's proven schedule (stage K,V -> vmcnt(0) -> compute;
// r4-r6 proved choreography is not the lever). Rolled kt loop (unroll
// spills, r1/r2/r4). LDS 53248 -> 3 blocks/CU ceiling (launch_bounds 256,3).
// 1-D grid, hb = id&63: same-(b,h) blocks share id%8 -> same XCD L2
// (FETCH 70MB -> 12MB, proven r5).
// Partial O (64x64 f32) and l per wave are reduced across waves at the end.
// ---------------------------------------------------------------------------
__global__ __launch_bounds__(256, 3) void attn_mfma(
    const unsigned short* __restrict__ qkv, const unsigned short* __restrict__ vt,
    unsigned short* __restrict__ attn_o) {
  // per-wave: Ks 4KB | VTs 4KB | Ps 5120B = 13312 B; x4 waves = 53248 B.
  // end-of-kernel overlay: Obuf f32[4*1024] (16KB) | lbuf f32[256] | linv f32[64]
  __shared__ char sm[53248];
  const int hb = blockIdx.x & 63;         // same-(b,h) blocks -> same XCD
  const int qt = blockIdx.x >> 6;
  const int h = hb & 7, b = hb >> 3;
  const int t = threadIdx.x;
  const int wv = t >> 6, lane = t & 63;
  const int lo = lane & 15, hi = lane >> 4;

  char* wbase = sm + wv * 13312;
  short* Ks  = (short*)(wbase);
  short* VTs = (short*)(wbase + 4096);
  short* Ps  = (short*)(wbase + 8192);  // [64 q-rows][40] (32 k-cols + pad 8)

  const short* qb = (const short*)qkv + ((size_t)(0 * BB + b) * NPIX) * DIMC + h * DHEAD;
  const short* kb = (const short*)qkv + ((size_t)(1 * BB + b) * NPIX) * DIMC + h * DHEAD;
  const short* vtb = (const short*)vt + ((size_t)(b * NHEAD + h)) * DHEAD * NPIX;

  // Q A-frags for all 64 q-rows: [mt][cc]
  short8 qf[4][2];
  #pragma unroll
  for (int mt = 0; mt < 4; ++mt)
    #pragma unroll
    for (int cc = 0; cc < 2; ++cc)
      qf[mt][cc] = *reinterpret_cast<const short8*>(
          qb + (size_t)(qt * 64 + mt * 16 + lo) * DIMC + cc * 32 + hi * 8);

  float4v oacc[4][4];
  float lsum[4];
  #pragma unroll
  for (int mt = 0; mt < 4; ++mt) {
    lsum[mt] = 0.f;
    #pragma unroll
    for (int dt = 0; dt < 4; ++dt) oacc[mt][dt] = {0.f, 0.f, 0.f, 0.f};
  }

  const int n0 = wv * 256;  // this wave's private k-column strip
  // per-lane Ps write base (shorts); per-(mt,nt) offset is a compile-time imm
  short* PsW = Ps + lo * 40 + hi * 4;

  for (int kt = 0; kt < 8; ++kt) {  // ROLLED — do not unroll (spill hazard)
    const int kbase = n0 + kt * 32;
    // prior tile's ds_reads must drain before LDS is overwritten
    __builtin_amdgcn_s_waitcnt(WAITCNT_LGKM0);
    __builtin_amdgcn_sched_barrier(0);
    #pragma unroll
    for (int s = 0; s < 4; ++s) {
      const int nt = s >> 1, cc = s & 1;
      async16(kb + (size_t)(kbase + nt * 16 + lo) * DIMC + cc * 32 + hi * 8,
              Ks + (s * 64 + lane) * 8);
    }
    #pragma unroll
    for (int dt = 0; dt < 4; ++dt)
      async16(vtb + (size_t)(dt * 16 + lo) * NPIX + kbase + hi * 8,
              VTs + (dt * 64 + lane) * 8);
    __builtin_amdgcn_sched_barrier(0);
    __builtin_amdgcn_s_waitcnt(WAITCNT_VM0);
    __builtin_amdgcn_sched_barrier(0);

    // S^T = K Q^T (operand-swapped): sacc[mt][nt] reg r =
    //   S[k' = nt*16 + hi*4 + r][q = mt*16 + lo]
    short8 kf[2][2];
    #pragma unroll
    for (int nt = 0; nt < 2; ++nt)
      #pragma unroll
      for (int cc = 0; cc < 2; ++cc)
        kf[nt][cc] = *reinterpret_cast<const short8*>(Ks + ((nt * 2 + cc) * 64 + lane) * 8);
    float4v sacc[4][2];
    #pragma unroll
    for (int mt = 0; mt < 4; ++mt)
      #pragma unroll
      for (int nt = 0; nt < 2; ++nt) {
        sacc[mt][nt] = {0.f, 0.f, 0.f, 0.f};
        sacc[mt][nt] = __builtin_amdgcn_mfma_f32_16x16x32_bf16(kf[nt][0], qf[mt][0],
                                                               sacc[mt][nt], 0, 0, 0);
        sacc[mt][nt] = __builtin_amdgcn_mfma_f32_16x16x32_bf16(kf[nt][1], qf[mt][1],
                                                               sacc[mt][nt], 0, 0, 0);
      }

    // p = exp(s) (fast __expf); pack pairs (RNE), 1 b64 store per (mt,nt).
    // Row q = mt*16+lo; cols nt*16+hi*4 .. +3 — consecutive in r.
    #pragma unroll
    for (int mt = 0; mt < 4; ++mt) {
      const float p00 = __expf(sacc[mt][0][0]);
      const float p01 = __expf(sacc[mt][0][1]);
      const float p02 = __expf(sacc[mt][0][2]);
      const float p03 = __expf(sacc[mt][0][3]);
      const float p10 = __expf(sacc[mt][1][0]);
      const float p11 = __expf(sacc[mt][1][1]);
      const float p12 = __expf(sacc[mt][1][2]);
      const float p13 = __expf(sacc[mt][1][3]);
      uint2 w0, w1;
      w0.x = cvt_pk_bf16(p00, p01); w0.y = cvt_pk_bf16(p02, p03);
      w1.x = cvt_pk_bf16(p10, p11); w1.y = cvt_pk_bf16(p12, p13);
      *reinterpret_cast<uint2*>(PsW + mt * 640) = w0;        // nt=0
      *reinterpret_cast<uint2*>(PsW + mt * 640 + 16) = w1;   // nt=1
      lsum[mt] += ((p00 + p01) + (p02 + p03)) + ((p10 + p11) + (p12 + p13));
    }

    // O += P V   (P A-frags from wave-private LDS — read path unchanged;
    //             VT B-frags frag-order)
    short8 vf[4];
    #pragma unroll
    for (int dt = 0; dt < 4; ++dt)
      vf[dt] = *reinterpret_cast<const short8*>(VTs + (dt * 64 + lane) * 8);
    #pragma unroll
    for (int mt = 0; mt < 4; ++mt) {
      const short8 pf = *reinterpret_cast<const short8*>(Ps + (mt * 16 + lo) * 40 + hi * 8);
      #pragma unroll
      for (int dt = 0; dt < 4; ++dt)
        oacc[mt][dt] = __builtin_amdgcn_mfma_f32_16x16x32_bf16(pf, vf[dt],
                                                               oacc[mt][dt], 0, 0, 0);
    }
  }

  // reduce l across the 4 hi-groups sharing each q (= lo) row
  float lv[4];
  #pragma unroll
  for (int mt = 0; mt < 4; ++mt) {
    float v = lsum[mt];
    v += __shfl_xor(v, 16);
    v += __shfl_xor(v, 32);
    lv[mt] = v;
  }

  float* Obuf = (float*)sm;               // 16 KB
  float* lbuf = (float*)(sm + 16384);     // 4*64 f32
  float* linv = (float*)(sm + 17408);     // 64 f32
  __syncthreads();  // all waves done with private LDS
  if (hi == 0) {
    #pragma unroll
    for (int mt = 0; mt < 4; ++mt) lbuf[wv * 64 + mt * 16 + lo] = lv[mt];
  }
  __syncthreads();
  if (t < 64) linv[t] = 1.0f / (lbuf[t] + lbuf[64 + t] + lbuf[128 + t] + lbuf[192 + t]);

  unsigned short* aob = attn_o + ((size_t)b * NPIX + qt * 64) * DIMC + h * DHEAD;
  #pragma unroll
  for (int mt = 0; mt < 4; ++mt) {
    __syncthreads();
    #pragma unroll
    for (int dt = 0; dt < 4; ++dt)
      #pragma unroll
      for (int r = 0; r < 4; ++r)
        Obuf[wv * 1024 + (dt * 4 + r) * 64 + lane] = oacc[mt][dt][r];
    __syncthreads();
    #pragma unroll
    for (int k2 = 0; k2 < 4; ++k2) {
      const int e = t + k2 * 256;
      const float sum2 = Obuf[e] + Obuf[1024 + e] + Obuf[2048 + e] + Obuf[3072 + e];
      const int dt = e >> 8, r = (e >> 6) & 3, le = e & 63;
      const int row = mt * 16 + (le >> 4) * 4 + r, d = dt * 16 + (le & 15);
      aob[(size_t)row * DIMC + d] = f2b(sum2 * linv[row]);
    }
  }
}

// ---------------------------------------------------------------------------
extern "C" void kernel_launch(void* const* d_in, const int* in_sizes, int n_in,
                              void* d_out, int out_size, void* d_ws, size_t ws_size,
                              hipStream_t stream) {
  const float* x    = (const float*)d_in[0];
  const float* dw_w = (const float*)d_in[1];
  const float* dw_b = (const float*)d_in[2];
  const float* bn_g = (const float*)d_in[3];
  const float* bn_b = (const float*)d_in[4];
  const float* bn_m = (const float*)d_in[5];
  const float* bn_v = (const float*)d_in[6];
  const float* pw_w = (const float*)d_in[7];
  const float* pw_b = (const float*)d_in[8];
  const float* out_w = (const float*)d_in[9];
  const float* out_b = (const float*)d_in[10];
  float* out = (float*)d_out;

  // Workspace layout (bf16 bits as unsigned short):
  //   z      [3][B][N][512]  = 12582912 elems (25.2 MB)
  //   qkv    [3][B][N][512]  = 12582912 elems (25.2 MB)
  //   wbf    pw_w|out_w bf16 =  1048576 elems ( 2.1 MB)
  //   bb     scaled pw_b f32 =  1536
  //   wT     dw tap-major f32 = 3*9*512 = 13824
  //   shiftv folded BN f32   =  1536
  // After the qkv GEMM, z is dead: VT (8.4MB) and attn_o (8.4MB) overlay it.
  unsigned short* z   = (unsigned short*)d_ws;
  unsigned short* qkv = z + (size_t)3 * BB * NPIX * DIMC;
  unsigned short* wbf = qkv + (size_t)3 * BB * NPIX * DIMC;
  float* bb = (float*)(wbf + (size_t)4 * DIMC * DIMC);
  float* wT = bb + 3 * DIMC;
  float* shiftv = wT + 3 * 9 * DIMC;
  unsigned short* vtb = z;
  unsigned short* attn_o = z + (size_t)BB * NHEAD * DHEAD * NPIX;

  wcvt_kernel<<<dim3(1024), 256, 0, stream>>>(pw_w, out_w, pw_b, dw_w, dw_b,
                                              bn_g, bn_b, bn_m, bn_v, wbf, bb,
                                              wT, shiftv);
  dwbn_kernel<<<dim3(16, 8, BB), 256, 0, stream>>>(x, wT, shiftv, z);
  // qkv = z * pw_w^T + bb  (24 batches, XCD-chunked 1-D grid 768)
  gemm_mfma<unsigned short, 24><<<dim3(768), 256, 0, stream>>>(z, wbf, bb, qkv);
  // VT for PV B-operand
  vt_kernel<<<dim3(16, NHEAD, BB), 256, 0, stream>>>(
      qkv + (size_t)2 * BB * NPIX * DIMC, vtb);
  // attention (1-D grid: hb-major for XCD L2 locality)
  attn_mfma<<<dim3(1024), 256, 0, stream>>>(qkv, vtb, attn_o);
  // out = attn_o * out_w^T + out_b (8 batches, XCD-chunked 1-D grid 256)
  gemm_mfma<float, 8><<<dim3(256), 256, 0, stream>>>(
      attn_o, wbf + (size_t)3 * DIMC * DIMC, out_b, out);
}